// Round 8
// baseline (523.520 us; speedup 1.0000x reference)
//
#include <hip/hip_runtime.h>
#include <hip/hip_bf16.h>
#include <hip/hip_cooperative_groups.h>

namespace cg = cooperative_groups;

// GraphSAGEConv: N=50000 nodes, E=800000 edges, D=64 in/out, fp32.
// out = x @ W_self^T + b_self + scatter_mean(x[col] -> row) @ W_neigh^T + b_neigh
//
// R8: cooperative mega-kernel with occupancy-queried grid + error-checked
// fallback cascade (coop@G -> coop@256 -> R6 split pipeline). All paths
// deterministic per call.
//
// ws layout (ints): [cnt: N][cursor: N][off: N+1][bsum: 1024][boff: 1024]
//                   [sorted: E][flag: 1]

#define D 64
#define NPB 8        // nodes (waves) per 512-thread block in fused phase
#define TPB 512

__device__ __forceinline__ int load_idx(const void* ei, int use64, long long pos) {
    if (use64) return (int)((const long long*)ei)[pos];
    return ((const int*)ei)[pos];
}

// ================= cooperative mega-kernel ==================================
__device__ __forceinline__ int block_scan_excl512(int v, int t, int* total,
                                                  int* wsum_s /*[8] shared*/) {
    int lane = t & 63, wid = t >> 6;
    int sc = v;
    #pragma unroll
    for (int o = 1; o < 64; o <<= 1) {
        int u = __shfl_up(sc, o);
        if (lane >= o) sc += u;
    }
    if (lane == 63) wsum_s[wid] = sc;
    __syncthreads();
    int woff = 0, tot = 0;
    #pragma unroll
    for (int ww = 0; ww < 8; ++ww) {
        int s = wsum_s[ww];
        woff += (ww < wid) ? s : 0;
        tot += s;
    }
    __syncthreads();
    *total = tot;
    return woff + sc - v;
}

__global__ __launch_bounds__(TPB, 8) void mega_k(
        const float* __restrict__ x, const void* __restrict__ ei,
        const float* __restrict__ Ws, const float* __restrict__ bs,
        const float* __restrict__ Wn, const float* __restrict__ bn,
        float* __restrict__ out,
        int* cnt, int* cursor, int* off, int* bsum, int* boff,
        int* sorted, int* flag, int N, int E) {
    cg::grid_group grid = cg::this_grid();

    __shared__ float sWs[D][D + 1];
    __shared__ float sWn[D][D + 1];
    __shared__ float sx[NPB][D];
    __shared__ float sm[NPB][D];
    __shared__ int   wsum_s[8];

    const int t   = threadIdx.x;
    const int bid = blockIdx.x;
    const int tid = bid * TPB + t;
    const int NT  = gridDim.x * TPB;

    for (int i = t; i < D * D; i += TPB) {
        sWs[i >> 6][i & 63] = Ws[i];
        sWn[i >> 6][i & 63] = Wn[i];
    }
    __syncthreads();

    // ---- P1: zero cnt/cursor + dtype detect --------------------------------
    for (int i = tid; i < N; i += NT) { cnt[i] = 0; cursor[i] = 0; }
    if (tid < 64) {
        long long v = (t < 16) ? ((const long long*)ei)[t] : 0;
        unsigned long long bad = __ballot(t < 16 && (v < 0 || v >= (long long)N));
        if (t == 0) *flag = (bad == 0ULL) ? 1 : 0;
    }
    grid.sync();

    // ---- P2: histogram of destinations -------------------------------------
    const int use64 = *flag;
    for (int e = tid; e < E; e += NT) {
        int r = load_idx(ei, use64, e);
        atomicAdd(&cnt[r], 1);
    }
    grid.sync();

    // ---- P3a: per-block exclusive scan (1 elem/thread; needs G*512 >= N) ---
    {
        int i = tid;
        int v = (i < N) ? cnt[i] : 0;
        int total;
        int ex = block_scan_excl512(v, t, &total, wsum_s);
        if (i < N) off[i] = ex;
        if (t == 0) bsum[bid] = total;
    }
    grid.sync();

    // ---- P3b: block 0 scans the block totals (NBB = ceil(N/512) <= 512) ----
    const int NBB = (N + TPB - 1) / TPB;
    if (bid == 0) {
        int v = (t < NBB) ? bsum[t] : 0;
        int total;
        int ex = block_scan_excl512(v, t, &total, wsum_s);
        if (t < NBB) boff[t] = ex;
    }
    grid.sync();

    // ---- P4: scatter col indices into CSR order ----------------------------
    for (int e = tid; e < E; e += NT) {
        int r = load_idx(ei, use64, e);
        int c = load_idx(ei, use64, (long long)E + e);
        int p = atomicAdd(&cursor[r], 1);
        sorted[off[r] + boff[r >> 9] + p] = c;
    }
    grid.sync();

    // ---- P5: fused gather-mean + dual linear -------------------------------
    const int w  = t >> 6;
    const int f  = t & 63;
    const int q  = f & 15;
    const int j4 = f >> 4;
    const int NG = (N + NPB - 1) / NPB;

    for (int g = bid; g < NG; g += gridDim.x) {
        __syncthreads();
        int n = g * NPB + w;
        if (n < N) {
            int a = off[n] + boff[n >> 9];
            int b = (n + 1 < N) ? (off[n + 1] + boff[(n + 1) >> 9]) : E;
            float4 acc = make_float4(0.f, 0.f, 0.f, 0.f);
            for (int base = a; base < b; base += 64) {
                int rem = b - base;
                int cl = (f < rem) ? sorted[base + f] : 0;
                int m = rem < 64 ? rem : 64;
                for (int jj = 0; jj < m; jj += 4) {
                    int slot = jj + j4;
                    int c = __shfl(cl, slot);
                    if (slot < m) {
                        float4 v = *(const float4*)&x[c * D + 4 * q];
                        acc.x += v.x; acc.y += v.y; acc.z += v.z; acc.w += v.w;
                    }
                }
            }
            #pragma unroll
            for (int o = 16; o < 64; o <<= 1) {
                acc.x += __shfl_xor(acc.x, o);
                acc.y += __shfl_xor(acc.y, o);
                acc.z += __shfl_xor(acc.z, o);
                acc.w += __shfl_xor(acc.w, o);
            }
            int deg = b - a;
            float dinv = (deg > 0) ? 1.0f / (float)deg : 0.0f;
            if (j4 == 0) {
                float4 mv = make_float4(acc.x * dinv, acc.y * dinv,
                                        acc.z * dinv, acc.w * dinv);
                *(float4*)&sm[w][4 * q] = mv;
            }
            sx[w][f] = x[n * D + f];
        }
        __syncthreads();
        if (n < N) {
            float acco = bs[f] + bn[f];
            #pragma unroll
            for (int k = 0; k < D; ++k) {
                acco += sWs[f][k] * sx[w][k] + sWn[f][k] * sm[w][k];
            }
            out[n * D + f] = acco;
        }
    }
}

// ================= R6-proven split-kernel fallback ==========================
__global__ void detect_k(const long long* __restrict__ ei, int* __restrict__ flag, int n) {
    int t = threadIdx.x;
    long long v = (t < 16) ? ei[t] : 0;
    unsigned long long bad = __ballot(t < 16 && (v < 0 || v >= (long long)n));
    if (t == 0) *flag = (bad == 0ULL) ? 1 : 0;
}

__global__ __launch_bounds__(256) void hist_k(
        const void* __restrict__ ei, const int* __restrict__ flag,
        int* __restrict__ cnt, int E) {
    int e = blockIdx.x * 256 + threadIdx.x;
    if (e >= E) return;
    int use64 = *flag;
    int r = load_idx(ei, use64, e);
    atomicAdd(&cnt[r], 1);
}

__device__ __forceinline__ int block_scan_excl256(int v, int t, int* total) {
    __shared__ int ws4[4];
    int lane = t & 63, wid = t >> 6;
    int sc = v;
    #pragma unroll
    for (int o = 1; o < 64; o <<= 1) {
        int u = __shfl_up(sc, o);
        if (lane >= o) sc += u;
    }
    if (lane == 63) ws4[wid] = sc;
    __syncthreads();
    int woff = 0, tot = 0;
    #pragma unroll
    for (int ww = 0; ww < 4; ++ww) {
        int s = ws4[ww];
        woff += (ww < wid) ? s : 0;
        tot += s;
    }
    *total = tot;
    return woff + sc - v;
}

__global__ __launch_bounds__(256) void scan1_k(
        const int* __restrict__ cnt, int* __restrict__ off,
        int* __restrict__ bsum, int N) {
    int t = threadIdx.x;
    int i = blockIdx.x * 256 + t;
    int v = (i < N) ? cnt[i] : 0;
    int total;
    int ex = block_scan_excl256(v, t, &total);
    if (i <= N) off[i] = ex;
    if (t == 0) bsum[blockIdx.x] = total;
}

__global__ __launch_bounds__(256) void scan2_k(
        const int* __restrict__ bsum, int* __restrict__ boff, int NB) {
    int t = threadIdx.x;
    int v = (t < NB) ? bsum[t] : 0;
    int total;
    int ex = block_scan_excl256(v, t, &total);
    if (t < NB) boff[t] = ex;
}

__global__ __launch_bounds__(256) void scatter_edges_k(
        const void* __restrict__ ei, const int* __restrict__ flag,
        const int* __restrict__ off, const int* __restrict__ boff,
        int* __restrict__ cursor, int* __restrict__ sorted, int E) {
    int e = blockIdx.x * 256 + threadIdx.x;
    if (e >= E) return;
    int use64 = *flag;
    int r = load_idx(ei, use64, e);
    int c = load_idx(ei, use64, (long long)E + e);
    int p = atomicAdd(&cursor[r], 1);
    sorted[off[r] + boff[r >> 8] + p] = c;
}

__global__ __launch_bounds__(512, 8) void fused_k(
        const float* __restrict__ x,
        const int* __restrict__ off, const int* __restrict__ boff,
        const int* __restrict__ sorted,
        const float* __restrict__ Ws, const float* __restrict__ bs,
        const float* __restrict__ Wn, const float* __restrict__ bn,
        float* __restrict__ out, int N) {
    __shared__ float sWs[D][D + 1];
    __shared__ float sWn[D][D + 1];
    __shared__ float sx[NPB][D];
    __shared__ float sm[NPB][D];

    int t = threadIdx.x;
    for (int i = t; i < D * D; i += 512) {
        sWs[i >> 6][i & 63] = Ws[i];
        sWn[i >> 6][i & 63] = Wn[i];
    }

    int w = t >> 6;
    int f = t & 63;
    int q = f & 15;
    int j4 = f >> 4;
    int n = blockIdx.x * NPB + w;
    if (n < N) {
        int a = off[n] + boff[n >> 8];
        int b = off[n + 1] + boff[(n + 1) >> 8];
        float4 acc = make_float4(0.f, 0.f, 0.f, 0.f);
        for (int base = a; base < b; base += 64) {
            int rem = b - base;
            int cl = (f < rem) ? sorted[base + f] : 0;
            int m = rem < 64 ? rem : 64;
            for (int jj = 0; jj < m; jj += 4) {
                int slot = jj + j4;
                int c = __shfl(cl, slot);
                if (slot < m) {
                    float4 v = *(const float4*)&x[c * D + 4 * q];
                    acc.x += v.x; acc.y += v.y; acc.z += v.z; acc.w += v.w;
                }
            }
        }
        #pragma unroll
        for (int o = 16; o < 64; o <<= 1) {
            acc.x += __shfl_xor(acc.x, o);
            acc.y += __shfl_xor(acc.y, o);
            acc.z += __shfl_xor(acc.z, o);
            acc.w += __shfl_xor(acc.w, o);
        }
        int deg = b - a;
        float dinv = (deg > 0) ? 1.0f / (float)deg : 0.0f;
        if (j4 == 0) {
            float4 mv = make_float4(acc.x * dinv, acc.y * dinv,
                                    acc.z * dinv, acc.w * dinv);
            *(float4*)&sm[w][4 * q] = mv;
        }
        sx[w][f] = x[n * D + f];
    }
    __syncthreads();
    if (n >= N) return;

    float acco = bs[f] + bn[f];
#pragma unroll
    for (int k = 0; k < D; ++k) {
        acco += sWs[f][k] * sx[w][k] + sWn[f][k] * sm[w][k];
    }
    out[n * D + f] = acco;
}

// ================= host launcher ============================================
extern "C" void kernel_launch(void* const* d_in, const int* in_sizes, int n_in,
                              void* d_out, int out_size, void* d_ws, size_t ws_size,
                              hipStream_t stream) {
    const float* x  = (const float*)d_in[0];
    const void*  ei = d_in[1];
    const float* Ws = (const float*)d_in[2];
    const float* bs = (const float*)d_in[3];
    const float* Wn = (const float*)d_in[4];
    const float* bn = (const float*)d_in[5];
    float* out = (float*)d_out;

    int N = in_sizes[0] / D;
    int E = in_sizes[1] / 2;

    int* cnt    = (int*)d_ws;
    int* cursor = cnt + N;
    int* off    = cursor + N;
    int* bsum   = off + N + 1;
    int* boff   = bsum + 1024;
    int* sorted = boff + 1024;
    int* flag   = sorted + E;

    // --- grid sizing from the runtime's own occupancy model ---
    int bpc = 0;
    hipError_t qerr = hipOccupancyMaxActiveBlocksPerMultiprocessor(
        &bpc, (const void*)mega_k, TPB, 0);
    if (qerr != hipSuccess || bpc < 1) bpc = 1;
    int G = bpc * 256;
    if (G > 1024) G = 1024;
    int NBBmin = (N + TPB - 1) / TPB;   // 98: scan needs G*TPB >= N
    if (G < NBBmin) G = NBBmin;

    void* args[] = { &x, &ei, &Ws, &bs, &Wn, &bn, &out,
                     &cnt, &cursor, &off, &bsum, &boff, &sorted, &flag,
                     &N, &E };

    hipError_t err = hipLaunchCooperativeKernel((const void*)mega_k, dim3(G),
                                                dim3(TPB), args, 0, stream);
    if (err != hipSuccess) {
        // second attempt: conservative 1 block/CU
        err = hipLaunchCooperativeKernel((const void*)mega_k, dim3(256),
                                         dim3(TPB), args, 0, stream);
    }
    if (err != hipSuccess) {
        // ---- R6-proven split pipeline fallback ----
        hipMemsetAsync(d_ws, 0, (size_t)2 * N * sizeof(int), stream);
        detect_k<<<1, 64, 0, stream>>>((const long long*)ei, flag, N);
        int eb = (E + 255) / 256;
        int NB = (N + 255) / 256;       // 196 <= 256
        hist_k<<<eb, 256, 0, stream>>>(ei, flag, cnt, E);
        scan1_k<<<NB, 256, 0, stream>>>(cnt, off, bsum, N);
        scan2_k<<<1, 256, 0, stream>>>(bsum, boff, NB);
        scatter_edges_k<<<eb, 256, 0, stream>>>(ei, flag, off, boff, cursor, sorted, E);
        fused_k<<<(N + NPB - 1) / NPB, 512, 0, stream>>>(x, off, boff, sorted,
                                                         Ws, bs, Wn, bn, out, N);
    }
}

// Round 9
// 203.192 us; speedup vs baseline: 2.5765x; 2.5765x over previous
//
#include <hip/hip_runtime.h>
#include <hip/hip_bf16.h>

// GraphSAGEConv: N=50000 nodes, E=800000 edges, D=64 in/out, fp32.
// out = x @ W_self^T + b_self + scatter_mean(x[col] -> row) @ W_neigh^T + b_neigh
//
// R9 = R6-proven CSR build + MFMA epilogue in fused_k:
//   out[16-node tile] = cat[x|mean] (16x128, bf16) @ WcatT (128x64, bf16)
// via 16x mfma_f32_16x16x32_bf16 per wave-tile. Kills the ~768 LDS-cyc/node
// VALU epilogue that bounded R6's fused_k.
//
// ws layout (ints): [cnt: N][cursor: N][off: N+1][bsum: 256][boff: 256]
//                   [sorted: E][flag: 1]

#define D   64
#define TPB 512
#define WPB 8      // waves per block
#define TPW 16     // nodes per wave tile

typedef __attribute__((ext_vector_type(8))) short bf16x8;
typedef __attribute__((ext_vector_type(4))) float f32x4;

__device__ __forceinline__ short f2bf(float f) {   // fp32 -> bf16 RNE
    unsigned u = __float_as_uint(f);
    unsigned r = (u + 0x7fffu + ((u >> 16) & 1u)) >> 16;
    return (short)r;
}

__device__ __forceinline__ int load_idx(const void* ei, int use64, long long pos) {
    if (use64) return (int)((const long long*)ei)[pos];
    return ((const int*)ei)[pos];
}

// ================= R6-proven CSR build ======================================
__global__ void detect_k(const long long* __restrict__ ei, int* __restrict__ flag, int n) {
    int t = threadIdx.x;
    long long v = (t < 16) ? ei[t] : 0;
    unsigned long long bad = __ballot(t < 16 && (v < 0 || v >= (long long)n));
    if (t == 0) *flag = (bad == 0ULL) ? 1 : 0;
}

__global__ __launch_bounds__(256) void hist_k(
        const void* __restrict__ ei, const int* __restrict__ flag,
        int* __restrict__ cnt, int E) {
    int e = blockIdx.x * 256 + threadIdx.x;
    if (e >= E) return;
    int use64 = *flag;
    int r = load_idx(ei, use64, e);
    atomicAdd(&cnt[r], 1);
}

__device__ __forceinline__ int block_scan_excl256(int v, int t, int* total) {
    __shared__ int ws4[4];
    int lane = t & 63, wid = t >> 6;
    int sc = v;
    #pragma unroll
    for (int o = 1; o < 64; o <<= 1) {
        int u = __shfl_up(sc, o);
        if (lane >= o) sc += u;
    }
    if (lane == 63) ws4[wid] = sc;
    __syncthreads();
    int woff = 0, tot = 0;
    #pragma unroll
    for (int ww = 0; ww < 4; ++ww) {
        int s = ws4[ww];
        woff += (ww < wid) ? s : 0;
        tot += s;
    }
    *total = tot;
    return woff + sc - v;
}

__global__ __launch_bounds__(256) void scan1_k(
        const int* __restrict__ cnt, int* __restrict__ off,
        int* __restrict__ bsum, int N) {
    int t = threadIdx.x;
    int i = blockIdx.x * 256 + t;
    int v = (i < N) ? cnt[i] : 0;
    int total;
    int ex = block_scan_excl256(v, t, &total);
    if (i <= N) off[i] = ex;
    if (t == 0) bsum[blockIdx.x] = total;
}

__global__ __launch_bounds__(256) void scan2_k(
        const int* __restrict__ bsum, int* __restrict__ boff, int NB) {
    int t = threadIdx.x;
    int v = (t < NB) ? bsum[t] : 0;
    int total;
    int ex = block_scan_excl256(v, t, &total);
    if (t < NB) boff[t] = ex;
}

__global__ __launch_bounds__(256) void scatter_edges_k(
        const void* __restrict__ ei, const int* __restrict__ flag,
        const int* __restrict__ off, const int* __restrict__ boff,
        int* __restrict__ cursor, int* __restrict__ sorted, int E) {
    int e = blockIdx.x * 256 + threadIdx.x;
    if (e >= E) return;
    int use64 = *flag;
    int r = load_idx(ei, use64, e);
    int c = load_idx(ei, use64, (long long)E + e);
    int p = atomicAdd(&cursor[r], 1);
    sorted[off[r] + boff[r >> 8] + p] = c;
}

// ================= fused gather-mean + MFMA dual linear =====================
// Wave owns 16 nodes. Gather: 4 passes, quarter-wave per node (lane ql loads
// float4 of features 4ql..4ql+3) -> mean as bf16 into per-wave LDS tile.
// Then D = A(16x128 bf16: [x | mean]) x B(WcatT in LDS) + bias via 16 MFMA.
// Layouts (HW-verified per guide): A[m=lane&15][k=quad*8+j],
// B[k=quad*8+j][n=lane&15], C/D col=lane&15 row=quad*4+reg.
__global__ __launch_bounds__(TPB) void fused_k(
        const float* __restrict__ x,
        const int* __restrict__ off, const int* __restrict__ boff,
        const int* __restrict__ sorted,
        const float* __restrict__ Ws, const float* __restrict__ bs,
        const float* __restrict__ Wn, const float* __restrict__ bn,
        float* __restrict__ out, int N) {
    __shared__ __align__(16) short wcat[D][136];         // WcatT[f][kk] bf16
    __shared__ __align__(16) short mtile[WPB][TPW][72];  // per-wave mean tiles

    const int t = threadIdx.x;
    // stage WcatT = [Ws | Wn] rows (f-major), bf16
    for (int i = t; i < D * 128; i += TPB) {
        int f = i >> 7, kk = i & 127;
        float v = (kk < D) ? Ws[f * D + kk] : Wn[f * D + (kk - D)];
        wcat[f][kk] = f2bf(v);
    }
    __syncthreads();   // only barrier; waves independent afterwards

    const int w    = t >> 6;
    const int lane = t & 63;
    const int m    = lane & 15;    // fragment row/col
    const int quad = lane >> 4;
    const int ql   = m;            // gather lane-in-quarter
    const int q4   = quad;         // gather quarter -> node slot

    int tile = (blockIdx.x * WPB + w) * TPW;
    if (tile >= N) return;

    // ---- gather phase ----
    for (int p = 0; p < 4; ++p) {
        int n = tile + p * 4 + q4;
        int a = 0, b = 0;
        if (n < N) {
            a = off[n] + boff[n >> 8];
            b = off[n + 1] + boff[(n + 1) >> 8];
        }
        float4 s = make_float4(0.f, 0.f, 0.f, 0.f);
        for (int base = a; base < b; base += 16) {
            int idx = (base + ql < b) ? sorted[base + ql] : 0;
            int mq = b - base; if (mq > 16) mq = 16;
            for (int j = 0; j < mq; ++j) {
                int c = __shfl(idx, (q4 << 4) + j);
                const float4 v = *(const float4*)&x[c * D + 4 * ql];
                s.x += v.x; s.y += v.y; s.z += v.z; s.w += v.w;
            }
        }
        int deg = b - a;
        float dinv = (deg > 0) ? 1.0f / (float)deg : 0.0f;
        short4 mv;
        mv.x = f2bf(s.x * dinv); mv.y = f2bf(s.y * dinv);
        mv.z = f2bf(s.z * dinv); mv.w = f2bf(s.w * dinv);
        *(short4*)&mtile[w][p * 4 + q4][4 * ql] = mv;   // 8B, wave-local
    }

    // ---- A fragments: ks 0,1 from x (global, cvt); ks 2,3 from mean LDS ----
    int nrow = tile + m;
    const float* xr = x + (size_t)(nrow < N ? nrow : N - 1) * D + quad * 8;
    bf16x8 afrag[4];
    #pragma unroll
    for (int ks = 0; ks < 2; ++ks) {
        const float* p0 = xr + ks * 32;
        float4 u0 = *(const float4*)p0;
        float4 u1 = *(const float4*)(p0 + 4);
        bf16x8 a;
        a[0] = f2bf(u0.x); a[1] = f2bf(u0.y); a[2] = f2bf(u0.z); a[3] = f2bf(u0.w);
        a[4] = f2bf(u1.x); a[5] = f2bf(u1.y); a[6] = f2bf(u1.z); a[7] = f2bf(u1.w);
        afrag[ks] = a;
    }
    #pragma unroll
    for (int ks = 2; ks < 4; ++ks) {
        afrag[ks] = *(const bf16x8*)&mtile[w][m][(ks - 2) * 32 + quad * 8];
    }

    // ---- MFMA: 4 f-tiles x 4 k-steps ----
    f32x4 acc[4];
    #pragma unroll
    for (int nf = 0; nf < 4; ++nf) {
        int fcol = nf * 16 + m;
        float bsum = bs[fcol] + bn[fcol];
        acc[nf] = (f32x4){bsum, bsum, bsum, bsum};
    }
    #pragma unroll
    for (int nf = 0; nf < 4; ++nf) {
        #pragma unroll
        for (int ks = 0; ks < 4; ++ks) {
            bf16x8 bfr = *(const bf16x8*)&wcat[nf * 16 + m][ks * 32 + quad * 8];
            acc[nf] = __builtin_amdgcn_mfma_f32_16x16x32_bf16(
                afrag[ks], bfr, acc[nf], 0, 0, 0);
        }
    }

    // ---- store: row = quad*4 + reg, col = nf*16 + m ----
    #pragma unroll
    for (int nf = 0; nf < 4; ++nf) {
        int fcol = nf * 16 + m;
        #pragma unroll
        for (int r = 0; r < 4; ++r) {
            int node = tile + quad * 4 + r;
            if (node < N) out[(size_t)node * D + fcol] = acc[nf][r];
        }
    }
}

// ================= host launcher ============================================
extern "C" void kernel_launch(void* const* d_in, const int* in_sizes, int n_in,
                              void* d_out, int out_size, void* d_ws, size_t ws_size,
                              hipStream_t stream) {
    const float* x  = (const float*)d_in[0];
    const void*  ei = d_in[1];
    const float* Ws = (const float*)d_in[2];
    const float* bs = (const float*)d_in[3];
    const float* Wn = (const float*)d_in[4];
    const float* bn = (const float*)d_in[5];
    float* out = (float*)d_out;

    int N = in_sizes[0] / D;
    int E = in_sizes[1] / 2;
    int NB = (N + 255) / 256;       // 196 <= 256

    int* cnt    = (int*)d_ws;
    int* cursor = cnt + N;
    int* off    = cursor + N;
    int* bsum   = off + N + 1;
    int* boff   = bsum + 256;
    int* sorted = boff + 256;
    int* flag   = sorted + E;

    hipMemsetAsync(d_ws, 0, (size_t)2 * N * sizeof(int), stream);
    detect_k<<<1, 64, 0, stream>>>((const long long*)ei, flag, N);

    int eb = (E + 255) / 256;
    hist_k<<<eb, 256, 0, stream>>>(ei, flag, cnt, E);
    scan1_k<<<NB, 256, 0, stream>>>(cnt, off, bsum, N);
    scan2_k<<<1, 256, 0, stream>>>(bsum, boff, NB);
    scatter_edges_k<<<eb, 256, 0, stream>>>(ei, flag, off, boff, cursor, sorted, E);

    int ntiles = (N + TPW - 1) / TPW;              // 3125
    int fblocks = (ntiles + WPB - 1) / WPB;        // 391
    fused_k<<<fblocks, TPB, 0, stream>>>(x, off, boff, sorted,
                                         Ws, bs, Wn, bn, out, N);
}